// Round 6
// baseline (27723.730 us; speedup 1.0000x reference)
//
#include <hip/hip_runtime.h>
#include <hip/hip_fp16.h>
#include <math.h>

// ESN recurrence, round 6: poll-fused matvec.
// Key change vs R5: each thread owns 4 COLUMNS x all 16 WG rows (w[16][4],
// 64 VGPRs at 512 threads/WG), so a thread's FMA inputs are exactly its own
// polled ring words. As each u64 tag locks in, its 2 columns are FMA'd into
// 16 row-partials immediately -- arrival spread hides under compute, only the
// last straggler's detect latency is exposed. Then: 96-op wave butterfly,
// cross-wave reduce via tiny double-buffered LDS (one barrier/step), 16-lane
// finalize (x-part dot computed early each step, off the critical path),
// one 64B coalesced tagged publish. Producers never stage state in LDS.
// Ring protocol unchanged: u32 = (tag=t+1)<<16 | f16(state); data self-
// validates; per-u64 lock-in (R5's fix); replay-stale values are bit-identical
// by determinism (benign); 0xAA poison tag never matches.

#define R_    2048
#define I_    32
#define O_    32
#define NSTEP 8191
#define G_    128
#define GR_   32
#define BLK   512
#define CAPP  (1u << 24)
#define CAPB  (1u << 22)

typedef unsigned int u32;
typedef unsigned long long u64;

__device__ __forceinline__ float tanh_fast(float u) {
    float e = __expf(2.f * u);            // inf-safe: overflow -> +/-1 exactly
    return 1.f - __fdividef(2.f, e + 1.f);
}
__device__ __forceinline__ u32 pkh(float v, u32 tag) {
    return (tag << 16) | (u32)__half_as_ushort(__float2half(v));
}
__device__ __forceinline__ u64 ald(const u64* p) {
    return __hip_atomic_load(p, __ATOMIC_RELAXED, __HIP_MEMORY_SCOPE_AGENT);
}
__device__ __forceinline__ float h2f(u32 bits16) {
    return __half2float(__ushort_as_half((unsigned short)(bits16 & 0xFFFFu)));
}

// ws layout: [0,128) rprog[32] ; [4096, 4096 + (dmask+1)*R_*4) ring u32[][R_]

__global__ __launch_bounds__(256) void esn_init(const float* __restrict__ X,
                                                const float* __restrict__ W_out,
                                                float* __restrict__ out,
                                                int* __restrict__ rprog)
{
    int idx = blockIdx.x * blockDim.x + threadIdx.x;
    if (idx < GR_)
        __hip_atomic_store(&rprog[idx], 0, __ATOMIC_RELAXED,
                           __HIP_MEMORY_SCOPE_AGENT);
    if (idx < NSTEP * O_) {
        int q = idx >> 5;
        int o = idx & 31;
        const float* wrow = W_out + o * (R_ + I_) + R_;
        const float* xrow = X + q * I_;
        float acc = 0.f;
        #pragma unroll
        for (int j = 0; j < I_; ++j) acc = fmaf(wrow[j], xrow[j], acc);
        out[idx] = acc;
    }
}

__global__ __launch_bounds__(BLK, 2) void esn_main(
    const float* __restrict__ X, const float* __restrict__ W_in,
    const float* __restrict__ W_res, const float* __restrict__ W_out,
    const float* __restrict__ state0, float* __restrict__ out,
    u32* __restrict__ ring, int* __restrict__ rprog, int dmask)
{
    const int tid = threadIdx.x;
    const int g   = blockIdx.x;
    __shared__ float pbuf[2][8][16];     // cross-wave row partials (producers)
    __shared__ float s_arr[R_];          // staged state (readers)

    if (g < G_) {
        // ------------- producer: rows [g*16, g*16+16) -------------
        const int lane = tid & 63;
        const int wave = tid >> 6;
        const int row0 = g * 16;
        const bool fin = (wave == 0) && (lane < 16);   // finalizer lanes

        // W_res slice: w[r] = rows row0+r, cols 4*tid .. 4*tid+3.
        // Each load: 512 threads x 16B = one full 8KB row, fully coalesced.
        float4 w[16];
        #pragma unroll
        for (int r = 0; r < 16; ++r)
            w[r] = *reinterpret_cast<const float4*>(
                W_res + (size_t)(row0 + r) * R_ + 4 * tid);
        #pragma unroll
        for (int r = 0; r < 16; ++r)
            asm volatile("" : "+v"(w[r].x), "+v"(w[r].y),
                              "+v"(w[r].z), "+v"(w[r].w));

        // W_in row for finalizer lanes (lane<16 of wave0 holds its row)
        float win[32];
        #pragma unroll
        for (int k = 0; k < 8; ++k) {
            float4 v = fin ? *reinterpret_cast<const float4*>(
                                 W_in + (size_t)(row0 + lane) * I_ + 4 * k)
                           : float4{0.f, 0.f, 0.f, 0.f};
            win[4*k+0] = v.x; win[4*k+1] = v.y;
            win[4*k+2] = v.z; win[4*k+3] = v.w;
        }

        for (int t = 0; t < NSTEP; ++t) {
            // gentle sampled back-pressure (R3 params) before overwriting
            // slot (t+1)&dmask (destroys tag t+1-(dmask+1) << reader min tag)
            if ((t & 15) == 0 && t > dmask) {
                unsigned tries = 0;
                while (__hip_atomic_load(&rprog[g & (GR_ - 1)], __ATOMIC_RELAXED,
                                         __HIP_MEMORY_SCOPE_AGENT) < t - 64) {
                    if (++tries > CAPB) break;
                    __builtin_amdgcn_s_sleep(16);
                }
            }

            // x-part dot for this step (finalizer lanes; issued early, its
            // ~200cy load + 32 FMA hide under the poll below)
            float ar = 0.f;
            if (fin) {
                const float* xr = X + (size_t)t * I_;
                #pragma unroll
                for (int k = 0; k < 8; ++k) {
                    float4 xv = *reinterpret_cast<const float4*>(xr + 4 * k);
                    ar = fmaf(win[4*k+0], xv.x, ar);
                    ar = fmaf(win[4*k+1], xv.y, ar);
                    ar = fmaf(win[4*k+2], xv.z, ar);
                    ar = fmaf(win[4*k+3], xv.w, ar);
                }
            }

            // poll-fused matvec: as each u64 (2 cols) locks in, FMA it.
            float part[16];
            #pragma unroll
            for (int r = 0; r < 16; ++r) part[r] = 0.f;

            if (t > 0) {   // t==0: s_0 = 0, nothing to poll, partials stay 0
                const u32 tg  = (u32)t;
                const u64 pat = ((u64)tg << 48) | ((u64)tg << 16);
                const u64 msk = 0xFFFF0000FFFF0000ull;
                const u64* p64 = (const u64*)(ring + (size_t)(t & dmask) * R_);
                unsigned pend = 0x3u, tries = 0;
                while (pend) {
                    u64 b0 = ald(&p64[2 * tid]);
                    u64 b1 = ald(&p64[2 * tid + 1]);
                    if ((pend & 1u) && !((b0 ^ pat) & msk)) {
                        float c0 = h2f((u32)b0), c1 = h2f((u32)(b0 >> 32));
                        #pragma unroll
                        for (int r = 0; r < 16; ++r)
                            part[r] = fmaf(w[r].x, c0, fmaf(w[r].y, c1, part[r]));
                        pend &= ~1u;
                    }
                    if ((pend & 2u) && !((b1 ^ pat) & msk)) {
                        float c2 = h2f((u32)b1), c3 = h2f((u32)(b1 >> 32));
                        #pragma unroll
                        for (int r = 0; r < 16; ++r)
                            part[r] = fmaf(w[r].z, c2, fmaf(w[r].w, c3, part[r]));
                        pend &= ~2u;
                    }
                    if (!pend) break;
                    if (++tries > CAPP) break;   // fail loud, never hang
                    __builtin_amdgcn_s_sleep(1);
                }
            }

            // wave butterfly: all 16 row-partials summed over 64 lanes
            #pragma unroll
            for (int off = 1; off < 64; off <<= 1) {
                #pragma unroll
                for (int r = 0; r < 16; ++r)
                    part[r] += __shfl_xor(part[r], off, 64);
            }
            // lanes 0..15: select own row (static chain), write LDS partial
            if (lane < 16) {
                float sel = part[0];
                #pragma unroll
                for (int r = 1; r < 16; ++r) sel = (lane == r) ? part[r] : sel;
                pbuf[t & 1][wave][lane] = sel;
            }
            __syncthreads();   // one barrier/step; pbuf double-buffered

            // finalize: 16 lanes of wave0 sum 8 wave-partials + x-part,
            // tanh, pack, one 64B coalesced tagged publish
            if (fin) {
                float s = pbuf[t & 1][0][lane] + pbuf[t & 1][1][lane]
                        + pbuf[t & 1][2][lane] + pbuf[t & 1][3][lane]
                        + pbuf[t & 1][4][lane] + pbuf[t & 1][5][lane]
                        + pbuf[t & 1][6][lane] + pbuf[t & 1][7][lane] + ar;
                float v = tanh_fast(s);
                __hip_atomic_store(&ring[(size_t)((t + 1) & dmask) * R_
                                         + row0 + lane],
                                   pkh(v, (u32)(t + 1)),
                                   __ATOMIC_RELAXED, __HIP_MEMORY_SCOPE_AGENT);
            }
            // no second barrier: other waves run ahead into the next poll,
            // which self-synchronizes on the data tags.
        }
    } else {
        // ------------- reader: steps t === r (mod 32) -------------
        const int r = g - G_;
        const int o = tid >> 4;            // output 0..31 (16 threads each)
        const int c = tid & 15;            // col-chunk (128 cols)
        const float* wrow = W_out + (size_t)o * (R_ + I_) + c * 128;

        for (int t = r; t < NSTEP; t += GR_) {
            const u32 tg  = (u32)(t + 1);
            const u64 pat = ((u64)tg << 48) | ((u64)tg << 16);
            const u64 msk = 0xFFFF0000FFFF0000ull;
            const u64* p64 = (const u64*)(ring + (size_t)((t + 1) & dmask) * R_);
            u64 a0 = 0, a1 = 0;
            unsigned pend = 0x3u, tries = 0;
            while (pend) {
                u64 b0 = ald(&p64[2 * tid]);
                u64 b1 = ald(&p64[2 * tid + 1]);
                if ((pend & 1u) && !((b0 ^ pat) & msk)) { a0 = b0; pend &= ~1u; }
                if ((pend & 2u) && !((b1 ^ pat) & msk)) { a1 = b1; pend &= ~2u; }
                if (!pend) break;
                if (++tries > CAPP) break;
                __builtin_amdgcn_s_sleep(2);
            }
            float4 f;
            f.x = h2f((u32)a0); f.y = h2f((u32)(a0 >> 32));
            f.z = h2f((u32)a1); f.w = h2f((u32)(a1 >> 32));
            *reinterpret_cast<float4*>(&s_arr[4 * tid]) = f;
            __syncthreads();
            if (tid == 0)
                __hip_atomic_store(&rprog[r], t, __ATOMIC_RELAXED,
                                   __HIP_MEMORY_SCOPE_AGENT);

            float acc0 = 0.f, acc1 = 0.f;
            #pragma unroll 8
            for (int j = 0; j < 128; j += 8) {
                float4 wv = *reinterpret_cast<const float4*>(wrow + j);
                float4 sv = *reinterpret_cast<const float4*>(&s_arr[c * 128 + j]);
                acc0 = fmaf(wv.x, sv.x, acc0); acc0 = fmaf(wv.y, sv.y, acc0);
                acc0 = fmaf(wv.z, sv.z, acc0); acc0 = fmaf(wv.w, sv.w, acc0);
                float4 wv2 = *reinterpret_cast<const float4*>(wrow + j + 4);
                float4 sv2 = *reinterpret_cast<const float4*>(&s_arr[c * 128 + j + 4]);
                acc1 = fmaf(wv2.x, sv2.x, acc1); acc1 = fmaf(wv2.y, sv2.y, acc1);
                acc1 = fmaf(wv2.z, sv2.z, acc1); acc1 = fmaf(wv2.w, sv2.w, acc1);
            }
            float acc = acc0 + acc1;
            acc += __shfl_xor(acc, 1, 64);
            acc += __shfl_xor(acc, 2, 64);
            acc += __shfl_xor(acc, 4, 64);
            acc += __shfl_xor(acc, 8, 64);
            if (c == 0) out[t * O_ + o] += acc;   // exclusive writer
            __syncthreads();                      // protect s_arr
        }
    }
}

extern "C" void kernel_launch(void* const* d_in, const int* in_sizes, int n_in,
                              void* d_out, int out_size, void* d_ws, size_t ws_size,
                              hipStream_t stream)
{
    (void)in_sizes; (void)n_in; (void)out_size;
    const float* X      = (const float*)d_in[0];
    const float* W_in   = (const float*)d_in[1];
    const float* W_res  = (const float*)d_in[2];
    const float* W_out  = (const float*)d_in[3];
    const float* state0 = (const float*)d_in[4];
    float* out = (float*)d_out;
    (void)state0;

    char* ws    = (char*)d_ws;
    int*  rprog = (int*)ws;
    u32*  ring  = (u32*)(ws + 4096);

    int dmask = (ws_size >= 4096 + (size_t)256 * R_ * 4) ? 255 : 127;

    hipLaunchKernelGGL(esn_init, dim3(1024), dim3(256), 0, stream,
                       X, W_out, out, rprog);
    hipLaunchKernelGGL(esn_main, dim3(G_ + GR_), dim3(BLK), 0, stream,
                       X, W_in, W_res, W_out, state0, out, ring, rprog, dmask);
}

// Round 7
// 26716.565 us; speedup vs baseline: 1.0377x; 1.0377x over previous
//
#include <hip/hip_runtime.h>
#include <hip/hip_fp16.h>
#include <math.h>

// ESN recurrence, round 7 = R5's sync structure + R2's register allocation.
// Regalloc evidence across rounds: scalar float arrays stay VGPR-resident
// (R2: w[4][32] -> VGPR 140), float4 arrays get sunk/rematerialized into the
// loop even with asm pins (R3/R5/R6: VGPR 84/92/76 -> 128KB/WG/step L2
// refetch). So: load W_res via float4, immediately decompose to 128 SCALAR
// floats, no asm pin. Keep R5's proven-correct sync: self-validating tagged
// ring (u32 = (tag=t+1)<<16 | f16), fused hoisted polls with per-u64 lock-in,
// double-buffered LDS state with ONE barrier/step, packed u64 publish from
// lane 0, gentle sampled back-pressure (every 16 steps @ t-64).

#define R_    2048
#define I_    32
#define O_    32
#define NSTEP 8191
#define G_    128
#define GR_   32
#define BLK   256
#define CAPP  (1u << 24)   // data-poll cap: fail loud, never hang
#define CAPB  (1u << 22)   // back-pressure cap

typedef unsigned int u32;
typedef unsigned long long u64;

__device__ __forceinline__ float tanh_fast(float u) {
    float e = __expf(2.f * u);            // inf-safe: overflow -> +/-1 exactly
    return 1.f - __fdividef(2.f, e + 1.f);
}
__device__ __forceinline__ u32 pkh(float v, u32 tag) {
    return (tag << 16) | (u32)__half_as_ushort(__float2half(v));
}
__device__ __forceinline__ u64 ald(const u64* p) {
    return __hip_atomic_load(p, __ATOMIC_RELAXED, __HIP_MEMORY_SCOPE_AGENT);
}
__device__ __forceinline__ float h2f(u32 b) {
    return __half2float(__ushort_as_half((unsigned short)(b & 0xFFFFu)));
}

// ws layout: [0,128) rprog[32] ; [4096, 4096 + (dmask+1)*R_*4) ring u32[][R_]

__global__ __launch_bounds__(256) void esn_init(const float* __restrict__ X,
                                                const float* __restrict__ W_out,
                                                float* __restrict__ out,
                                                int* __restrict__ rprog)
{
    int idx = blockIdx.x * blockDim.x + threadIdx.x;
    if (idx < GR_)
        __hip_atomic_store(&rprog[idx], 0, __ATOMIC_RELAXED,
                           __HIP_MEMORY_SCOPE_AGENT);
    if (idx < NSTEP * O_) {
        int q = idx >> 5;
        int o = idx & 31;
        const float* wrow = W_out + o * (R_ + I_) + R_;
        const float* xrow = X + q * I_;
        float acc = 0.f;
        #pragma unroll
        for (int j = 0; j < I_; ++j) acc = fmaf(wrow[j], xrow[j], acc);
        out[idx] = acc;
    }
}

__global__ __launch_bounds__(BLK, 1) void esn_main(
    const float* __restrict__ X, const float* __restrict__ W_in,
    const float* __restrict__ W_res, const float* __restrict__ W_out,
    const float* __restrict__ state0, float* __restrict__ out,
    u32* __restrict__ ring, int* __restrict__ rprog, int dmask)
{
    const int tid = threadIdx.x;
    const int g   = blockIdx.x;
    __shared__ float s_lds[2][R_];

    if (g < G_) {
        // ---------------- producer: rows [g*16, g*16+16) ----------------
        const int lane  = tid & 63;
        const int wave  = tid >> 6;
        const int myrow = g * 16 + wave * 4;    // this wave's 4 rows

        // W_res slice as 128 SCALAR floats (see header comment):
        // w[i][4k+j] = W_res[myrow+i][k*256 + 4*lane + j]
        float w[4][32];
        #pragma unroll
        for (int i = 0; i < 4; ++i) {
            const float* wr = W_res + (size_t)(myrow + i) * R_;
            #pragma unroll
            for (int k = 0; k < 8; ++k) {
                float4 v = *reinterpret_cast<const float4*>(wr + k * 256 + 4 * lane);
                w[i][4*k+0] = v.x; w[i][4*k+1] = v.y;
                w[i][4*k+2] = v.z; w[i][4*k+3] = v.w;
            }
        }
        float wi[4];
        #pragma unroll
        for (int i = 0; i < 4; ++i)
            wi[i] = (lane < 32) ? W_in[(size_t)(myrow + i) * I_ + lane] : 0.f;

        // seed s_0 into buffer 0
        #pragma unroll
        for (int q = 0; q < 8; ++q)
            s_lds[0][q * 256 + tid] = state0[q * 256 + tid];
        __syncthreads();

        float xl = (lane < 32) ? X[lane] : 0.f;

        for (int t = 0; t < NSTEP; ++t) {
            // gentle sampled back-pressure before overwriting slot (t+1)&dmask
            if ((t & 15) == 0 && t > dmask) {
                unsigned tries = 0;
                while (__hip_atomic_load(&rprog[g & (GR_ - 1)], __ATOMIC_RELAXED,
                                         __HIP_MEMORY_SCOPE_AGENT) < t - 64) {
                    if (++tries > CAPB) break;
                    __builtin_amdgcn_s_sleep(16);
                }
            }

            const float* sbuf = s_lds[t & 1];
            float p0 = wi[0] * xl, p1 = wi[1] * xl, p2 = wi[2] * xl, p3 = wi[3] * xl;
            #pragma unroll
            for (int k = 0; k < 8; ++k) {
                const float4 sv = *reinterpret_cast<const float4*>(
                    &sbuf[k * 256 + 4 * lane]);
                p0 = fmaf(w[0][4*k+0], sv.x, p0); p0 = fmaf(w[0][4*k+1], sv.y, p0);
                p0 = fmaf(w[0][4*k+2], sv.z, p0); p0 = fmaf(w[0][4*k+3], sv.w, p0);
                p1 = fmaf(w[1][4*k+0], sv.x, p1); p1 = fmaf(w[1][4*k+1], sv.y, p1);
                p1 = fmaf(w[1][4*k+2], sv.z, p1); p1 = fmaf(w[1][4*k+3], sv.w, p1);
                p2 = fmaf(w[2][4*k+0], sv.x, p2); p2 = fmaf(w[2][4*k+1], sv.y, p2);
                p2 = fmaf(w[2][4*k+2], sv.z, p2); p2 = fmaf(w[2][4*k+3], sv.w, p2);
                p3 = fmaf(w[3][4*k+0], sv.x, p3); p3 = fmaf(w[3][4*k+1], sv.y, p3);
                p3 = fmaf(w[3][4*k+2], sv.z, p3); p3 = fmaf(w[3][4*k+3], sv.w, p3);
            }
            #pragma unroll
            for (int off = 1; off < 64; off <<= 1) {
                p0 += __shfl_xor(p0, off, 64);
                p1 += __shfl_xor(p1, off, 64);
                p2 += __shfl_xor(p2, off, 64);
                p3 += __shfl_xor(p3, off, 64);
            }
            // publish: lane 0 packs 4 rows into 2 u64 tagged stores
            {
                const u32 tg = (u32)(t + 1);
                float v0 = tanh_fast(p0), v1 = tanh_fast(p1);
                float v2 = tanh_fast(p2), v3 = tanh_fast(p3);
                if (lane == 0) {
                    u64* dst = (u64*)(ring + (size_t)((t + 1) & dmask) * R_ + myrow);
                    u64 q0 = (u64)pkh(v0, tg) | ((u64)pkh(v1, tg) << 32);
                    u64 q1 = (u64)pkh(v2, tg) | ((u64)pkh(v3, tg) << 32);
                    __hip_atomic_store(&dst[0], q0, __ATOMIC_RELAXED,
                                       __HIP_MEMORY_SCOPE_AGENT);
                    __hip_atomic_store(&dst[1], q1, __ATOMIC_RELAXED,
                                       __HIP_MEMORY_SCOPE_AGENT);
                }
            }
            if (t == NSTEP - 1) break;

            float xn = (lane < 32) ? X[(size_t)(t + 1) * I_ + lane] : 0.f;

            // fused hoisted poll with per-u64 lock-in (R5's proven protocol)
            u64 a0 = 0, a1 = 0, a2 = 0, a3 = 0;
            {
                const u32 tg  = (u32)(t + 1);
                const u64 pat = ((u64)tg << 48) | ((u64)tg << 16);
                const u64 msk = 0xFFFF0000FFFF0000ull;
                const u64* p64 = (const u64*)(ring + (size_t)((t + 1) & dmask) * R_);
                unsigned pend = 0xFu, tries = 0;
                for (;;) {
                    u64 b0 = ald(&p64[0 * 256 + tid]);
                    u64 b1 = ald(&p64[1 * 256 + tid]);
                    u64 b2 = ald(&p64[2 * 256 + tid]);
                    u64 b3 = ald(&p64[3 * 256 + tid]);
                    if ((pend & 1u) && !((b0 ^ pat) & msk)) { a0 = b0; pend &= ~1u; }
                    if ((pend & 2u) && !((b1 ^ pat) & msk)) { a1 = b1; pend &= ~2u; }
                    if ((pend & 4u) && !((b2 ^ pat) & msk)) { a2 = b2; pend &= ~4u; }
                    if ((pend & 8u) && !((b3 ^ pat) & msk)) { a3 = b3; pend &= ~8u; }
                    if (!pend) break;
                    if (++tries > CAPP) break;   // fail loud, never hang
                    __builtin_amdgcn_s_sleep(1);
                }
            }
            // stage into the other buffer
            {
                float* dbuf = s_lds[(t + 1) & 1];
                float2 f;
                f.x = h2f((u32)a0); f.y = h2f((u32)(a0 >> 32));
                *reinterpret_cast<float2*>(&dbuf[0 * 512 + 2 * tid]) = f;
                f.x = h2f((u32)a1); f.y = h2f((u32)(a1 >> 32));
                *reinterpret_cast<float2*>(&dbuf[1 * 512 + 2 * tid]) = f;
                f.x = h2f((u32)a2); f.y = h2f((u32)(a2 >> 32));
                *reinterpret_cast<float2*>(&dbuf[2 * 512 + 2 * tid]) = f;
                f.x = h2f((u32)a3); f.y = h2f((u32)(a3 >> 32));
                *reinterpret_cast<float2*>(&dbuf[3 * 512 + 2 * tid]) = f;
            }
            xl = xn;
            __syncthreads();   // one barrier/step; double-buffer proven safe
        }
    } else {
        // ---------------- reader: steps t === r (mod 32) ----------------
        const int r = g - G_;
        const int o = tid >> 3;            // output 0..31
        const int c = tid & 7;             // col-chunk (256 cols)
        const float* wrow = W_out + (size_t)o * (R_ + I_) + c * 256;

        for (int t = r; t < NSTEP; t += GR_) {
            const u32 tg  = (u32)(t + 1);
            const u64 pat = ((u64)tg << 48) | ((u64)tg << 16);
            const u64 msk = 0xFFFF0000FFFF0000ull;
            const u64* p64 = (const u64*)(ring + (size_t)((t + 1) & dmask) * R_);
            u64 a0 = 0, a1 = 0, a2 = 0, a3 = 0;
            unsigned pend = 0xFu, tries = 0;
            for (;;) {
                u64 b0 = ald(&p64[0 * 256 + tid]);
                u64 b1 = ald(&p64[1 * 256 + tid]);
                u64 b2 = ald(&p64[2 * 256 + tid]);
                u64 b3 = ald(&p64[3 * 256 + tid]);
                if ((pend & 1u) && !((b0 ^ pat) & msk)) { a0 = b0; pend &= ~1u; }
                if ((pend & 2u) && !((b1 ^ pat) & msk)) { a1 = b1; pend &= ~2u; }
                if ((pend & 4u) && !((b2 ^ pat) & msk)) { a2 = b2; pend &= ~4u; }
                if ((pend & 8u) && !((b3 ^ pat) & msk)) { a3 = b3; pend &= ~8u; }
                if (!pend) break;
                if (++tries > CAPP) break;
                __builtin_amdgcn_s_sleep(2);
            }
            float2 f;
            f.x = h2f((u32)a0); f.y = h2f((u32)(a0 >> 32));
            *reinterpret_cast<float2*>(&s_lds[0][0 * 512 + 2 * tid]) = f;
            f.x = h2f((u32)a1); f.y = h2f((u32)(a1 >> 32));
            *reinterpret_cast<float2*>(&s_lds[0][1 * 512 + 2 * tid]) = f;
            f.x = h2f((u32)a2); f.y = h2f((u32)(a2 >> 32));
            *reinterpret_cast<float2*>(&s_lds[0][2 * 512 + 2 * tid]) = f;
            f.x = h2f((u32)a3); f.y = h2f((u32)(a3 >> 32));
            *reinterpret_cast<float2*>(&s_lds[0][3 * 512 + 2 * tid]) = f;
            __syncthreads();
            if (tid == 0)
                __hip_atomic_store(&rprog[r], t, __ATOMIC_RELAXED,
                                   __HIP_MEMORY_SCOPE_AGENT);

            float acc = 0.f;
            #pragma unroll 16
            for (int j = 0; j < 256; j += 4) {
                float4 wv = *reinterpret_cast<const float4*>(wrow + j);
                float4 sv = *reinterpret_cast<const float4*>(&s_lds[0][c * 256 + j]);
                acc = fmaf(wv.x, sv.x, acc);
                acc = fmaf(wv.y, sv.y, acc);
                acc = fmaf(wv.z, sv.z, acc);
                acc = fmaf(wv.w, sv.w, acc);
            }
            acc += __shfl_xor(acc, 1, 64);
            acc += __shfl_xor(acc, 2, 64);
            acc += __shfl_xor(acc, 4, 64);
            if (c == 0) out[t * O_ + o] += acc;   // exclusive writer
            __syncthreads();                      // protect s_lds before restage
        }
    }
}

extern "C" void kernel_launch(void* const* d_in, const int* in_sizes, int n_in,
                              void* d_out, int out_size, void* d_ws, size_t ws_size,
                              hipStream_t stream)
{
    (void)in_sizes; (void)n_in; (void)out_size;
    const float* X      = (const float*)d_in[0];
    const float* W_in   = (const float*)d_in[1];
    const float* W_res  = (const float*)d_in[2];
    const float* W_out  = (const float*)d_in[3];
    const float* state0 = (const float*)d_in[4];
    float* out = (float*)d_out;

    char* ws    = (char*)d_ws;
    int*  rprog = (int*)ws;
    u32*  ring  = (u32*)(ws + 4096);

    int dmask = (ws_size >= 4096 + (size_t)256 * R_ * 4) ? 255 : 127;

    hipLaunchKernelGGL(esn_init, dim3(1024), dim3(256), 0, stream,
                       X, W_out, out, rprog);
    hipLaunchKernelGGL(esn_main, dim3(G_ + GR_), dim3(BLK), 0, stream,
                       X, W_in, W_res, W_out, state0, out, ring, rprog, dmask);
}

// Round 8
// 26566.360 us; speedup vs baseline: 1.0436x; 1.0057x over previous
//
#include <hip/hip_runtime.h>
#include <hip/hip_fp16.h>
#include <math.h>

// ESN recurrence, round 8 = R7 + amdgpu_waves_per_eu(1,1).
// Residency audit across rounds: full W_res residency needs ~170 VGPRs
// (128 weight floats + ~40 loop-live). Measured VGPR_Count: R1=128, R2=140,
// R3=84, R5=92, R6=76, R7=92 -> the allocator NEVER granted it, because its
// occupancy heuristic targets multi-wave/EU unless capped. launch_bounds'
// 2nd arg only sets the MIN waves/EU. amdgpu_waves_per_eu(1,1) pins min=max=1
// -> full 512-VGPR budget, no reason to spill/remat the weights into the
// 8191-iteration loop. Our natural occupancy is 1 wave/SIMD anyway
// (160 WGs x 4 waves on 256 CUs), so the cap costs nothing.
// Everything else identical to R7 (single-variable change): self-validating
// tagged ring (u32 = (tag=t+1)<<16 | f16), hoisted lock-in polls, dbuf LDS +
// one barrier/step, packed u64 publish, sampled back-pressure.

#define R_    2048
#define I_    32
#define O_    32
#define NSTEP 8191
#define G_    128
#define GR_   32
#define BLK   256
#define CAPP  (1u << 24)   // data-poll cap: fail loud, never hang
#define CAPB  (1u << 22)   // back-pressure cap

typedef unsigned int u32;
typedef unsigned long long u64;

__device__ __forceinline__ float tanh_fast(float u) {
    float e = __expf(2.f * u);            // inf-safe: overflow -> +/-1 exactly
    return 1.f - __fdividef(2.f, e + 1.f);
}
__device__ __forceinline__ u32 pkh(float v, u32 tag) {
    return (tag << 16) | (u32)__half_as_ushort(__float2half(v));
}
__device__ __forceinline__ u64 ald(const u64* p) {
    return __hip_atomic_load(p, __ATOMIC_RELAXED, __HIP_MEMORY_SCOPE_AGENT);
}
__device__ __forceinline__ float h2f(u32 b) {
    return __half2float(__ushort_as_half((unsigned short)(b & 0xFFFFu)));
}

// ws layout: [0,128) rprog[32] ; [4096, 4096 + (dmask+1)*R_*4) ring u32[][R_]

__global__ __launch_bounds__(256) void esn_init(const float* __restrict__ X,
                                                const float* __restrict__ W_out,
                                                float* __restrict__ out,
                                                int* __restrict__ rprog)
{
    int idx = blockIdx.x * blockDim.x + threadIdx.x;
    if (idx < GR_)
        __hip_atomic_store(&rprog[idx], 0, __ATOMIC_RELAXED,
                           __HIP_MEMORY_SCOPE_AGENT);
    if (idx < NSTEP * O_) {
        int q = idx >> 5;
        int o = idx & 31;
        const float* wrow = W_out + o * (R_ + I_) + R_;
        const float* xrow = X + q * I_;
        float acc = 0.f;
        #pragma unroll
        for (int j = 0; j < I_; ++j) acc = fmaf(wrow[j], xrow[j], acc);
        out[idx] = acc;
    }
}

__global__ __launch_bounds__(BLK)
__attribute__((amdgpu_waves_per_eu(1, 1)))
void esn_main(
    const float* __restrict__ X, const float* __restrict__ W_in,
    const float* __restrict__ W_res, const float* __restrict__ W_out,
    const float* __restrict__ state0, float* __restrict__ out,
    u32* __restrict__ ring, int* __restrict__ rprog, int dmask)
{
    const int tid = threadIdx.x;
    const int g   = blockIdx.x;
    __shared__ float s_lds[2][R_];

    if (g < G_) {
        // ---------------- producer: rows [g*16, g*16+16) ----------------
        const int lane  = tid & 63;
        const int wave  = tid >> 6;
        const int myrow = g * 16 + wave * 4;    // this wave's 4 rows

        // W_res slice as 128 scalar floats:
        // w[i][4k+j] = W_res[myrow+i][k*256 + 4*lane + j]
        float w[4][32];
        #pragma unroll
        for (int i = 0; i < 4; ++i) {
            const float* wr = W_res + (size_t)(myrow + i) * R_;
            #pragma unroll
            for (int k = 0; k < 8; ++k) {
                float4 v = *reinterpret_cast<const float4*>(wr + k * 256 + 4 * lane);
                w[i][4*k+0] = v.x; w[i][4*k+1] = v.y;
                w[i][4*k+2] = v.z; w[i][4*k+3] = v.w;
            }
        }
        float wi[4];
        #pragma unroll
        for (int i = 0; i < 4; ++i)
            wi[i] = (lane < 32) ? W_in[(size_t)(myrow + i) * I_ + lane] : 0.f;

        // seed s_0 into buffer 0
        #pragma unroll
        for (int q = 0; q < 8; ++q)
            s_lds[0][q * 256 + tid] = state0[q * 256 + tid];
        __syncthreads();

        float xl = (lane < 32) ? X[lane] : 0.f;

        for (int t = 0; t < NSTEP; ++t) {
            // gentle sampled back-pressure before overwriting slot (t+1)&dmask
            if ((t & 15) == 0 && t > dmask) {
                unsigned tries = 0;
                while (__hip_atomic_load(&rprog[g & (GR_ - 1)], __ATOMIC_RELAXED,
                                         __HIP_MEMORY_SCOPE_AGENT) < t - 64) {
                    if (++tries > CAPB) break;
                    __builtin_amdgcn_s_sleep(16);
                }
            }

            const float* sbuf = s_lds[t & 1];
            float p0 = wi[0] * xl, p1 = wi[1] * xl, p2 = wi[2] * xl, p3 = wi[3] * xl;
            #pragma unroll
            for (int k = 0; k < 8; ++k) {
                const float4 sv = *reinterpret_cast<const float4*>(
                    &sbuf[k * 256 + 4 * lane]);
                p0 = fmaf(w[0][4*k+0], sv.x, p0); p0 = fmaf(w[0][4*k+1], sv.y, p0);
                p0 = fmaf(w[0][4*k+2], sv.z, p0); p0 = fmaf(w[0][4*k+3], sv.w, p0);
                p1 = fmaf(w[1][4*k+0], sv.x, p1); p1 = fmaf(w[1][4*k+1], sv.y, p1);
                p1 = fmaf(w[1][4*k+2], sv.z, p1); p1 = fmaf(w[1][4*k+3], sv.w, p1);
                p2 = fmaf(w[2][4*k+0], sv.x, p2); p2 = fmaf(w[2][4*k+1], sv.y, p2);
                p2 = fmaf(w[2][4*k+2], sv.z, p2); p2 = fmaf(w[2][4*k+3], sv.w, p2);
                p3 = fmaf(w[3][4*k+0], sv.x, p3); p3 = fmaf(w[3][4*k+1], sv.y, p3);
                p3 = fmaf(w[3][4*k+2], sv.z, p3); p3 = fmaf(w[3][4*k+3], sv.w, p3);
            }
            #pragma unroll
            for (int off = 1; off < 64; off <<= 1) {
                p0 += __shfl_xor(p0, off, 64);
                p1 += __shfl_xor(p1, off, 64);
                p2 += __shfl_xor(p2, off, 64);
                p3 += __shfl_xor(p3, off, 64);
            }
            // publish: lane 0 packs 4 rows into 2 u64 tagged stores
            {
                const u32 tg = (u32)(t + 1);
                float v0 = tanh_fast(p0), v1 = tanh_fast(p1);
                float v2 = tanh_fast(p2), v3 = tanh_fast(p3);
                if (lane == 0) {
                    u64* dst = (u64*)(ring + (size_t)((t + 1) & dmask) * R_ + myrow);
                    u64 q0 = (u64)pkh(v0, tg) | ((u64)pkh(v1, tg) << 32);
                    u64 q1 = (u64)pkh(v2, tg) | ((u64)pkh(v3, tg) << 32);
                    __hip_atomic_store(&dst[0], q0, __ATOMIC_RELAXED,
                                       __HIP_MEMORY_SCOPE_AGENT);
                    __hip_atomic_store(&dst[1], q1, __ATOMIC_RELAXED,
                                       __HIP_MEMORY_SCOPE_AGENT);
                }
            }
            if (t == NSTEP - 1) break;

            float xn = (lane < 32) ? X[(size_t)(t + 1) * I_ + lane] : 0.f;

            // fused hoisted poll with per-u64 lock-in
            u64 a0 = 0, a1 = 0, a2 = 0, a3 = 0;
            {
                const u32 tg  = (u32)(t + 1);
                const u64 pat = ((u64)tg << 48) | ((u64)tg << 16);
                const u64 msk = 0xFFFF0000FFFF0000ull;
                const u64* p64 = (const u64*)(ring + (size_t)((t + 1) & dmask) * R_);
                unsigned pend = 0xFu, tries = 0;
                for (;;) {
                    u64 b0 = ald(&p64[0 * 256 + tid]);
                    u64 b1 = ald(&p64[1 * 256 + tid]);
                    u64 b2 = ald(&p64[2 * 256 + tid]);
                    u64 b3 = ald(&p64[3 * 256 + tid]);
                    if ((pend & 1u) && !((b0 ^ pat) & msk)) { a0 = b0; pend &= ~1u; }
                    if ((pend & 2u) && !((b1 ^ pat) & msk)) { a1 = b1; pend &= ~2u; }
                    if ((pend & 4u) && !((b2 ^ pat) & msk)) { a2 = b2; pend &= ~4u; }
                    if ((pend & 8u) && !((b3 ^ pat) & msk)) { a3 = b3; pend &= ~8u; }
                    if (!pend) break;
                    if (++tries > CAPP) break;   // fail loud, never hang
                    __builtin_amdgcn_s_sleep(1);
                }
            }
            // stage into the other buffer
            {
                float* dbuf = s_lds[(t + 1) & 1];
                float2 f;
                f.x = h2f((u32)a0); f.y = h2f((u32)(a0 >> 32));
                *reinterpret_cast<float2*>(&dbuf[0 * 512 + 2 * tid]) = f;
                f.x = h2f((u32)a1); f.y = h2f((u32)(a1 >> 32));
                *reinterpret_cast<float2*>(&dbuf[1 * 512 + 2 * tid]) = f;
                f.x = h2f((u32)a2); f.y = h2f((u32)(a2 >> 32));
                *reinterpret_cast<float2*>(&dbuf[2 * 512 + 2 * tid]) = f;
                f.x = h2f((u32)a3); f.y = h2f((u32)(a3 >> 32));
                *reinterpret_cast<float2*>(&dbuf[3 * 512 + 2 * tid]) = f;
            }
            xl = xn;
            __syncthreads();   // one barrier/step; double-buffer proven safe
        }
    } else {
        // ---------------- reader: steps t === r (mod 32) ----------------
        const int r = g - G_;
        const int o = tid >> 3;            // output 0..31
        const int c = tid & 7;             // col-chunk (256 cols)
        const float* wrow = W_out + (size_t)o * (R_ + I_) + c * 256;

        for (int t = r; t < NSTEP; t += GR_) {
            const u32 tg  = (u32)(t + 1);
            const u64 pat = ((u64)tg << 48) | ((u64)tg << 16);
            const u64 msk = 0xFFFF0000FFFF0000ull;
            const u64* p64 = (const u64*)(ring + (size_t)((t + 1) & dmask) * R_);
            u64 a0 = 0, a1 = 0, a2 = 0, a3 = 0;
            unsigned pend = 0xFu, tries = 0;
            for (;;) {
                u64 b0 = ald(&p64[0 * 256 + tid]);
                u64 b1 = ald(&p64[1 * 256 + tid]);
                u64 b2 = ald(&p64[2 * 256 + tid]);
                u64 b3 = ald(&p64[3 * 256 + tid]);
                if ((pend & 1u) && !((b0 ^ pat) & msk)) { a0 = b0; pend &= ~1u; }
                if ((pend & 2u) && !((b1 ^ pat) & msk)) { a1 = b1; pend &= ~2u; }
                if ((pend & 4u) && !((b2 ^ pat) & msk)) { a2 = b2; pend &= ~4u; }
                if ((pend & 8u) && !((b3 ^ pat) & msk)) { a3 = b3; pend &= ~8u; }
                if (!pend) break;
                if (++tries > CAPP) break;
                __builtin_amdgcn_s_sleep(2);
            }
            float2 f;
            f.x = h2f((u32)a0); f.y = h2f((u32)(a0 >> 32));
            *reinterpret_cast<float2*>(&s_lds[0][0 * 512 + 2 * tid]) = f;
            f.x = h2f((u32)a1); f.y = h2f((u32)(a1 >> 32));
            *reinterpret_cast<float2*>(&s_lds[0][1 * 512 + 2 * tid]) = f;
            f.x = h2f((u32)a2); f.y = h2f((u32)(a2 >> 32));
            *reinterpret_cast<float2*>(&s_lds[0][2 * 512 + 2 * tid]) = f;
            f.x = h2f((u32)a3); f.y = h2f((u32)(a3 >> 32));
            *reinterpret_cast<float2*>(&s_lds[0][3 * 512 + 2 * tid]) = f;
            __syncthreads();
            if (tid == 0)
                __hip_atomic_store(&rprog[r], t, __ATOMIC_RELAXED,
                                   __HIP_MEMORY_SCOPE_AGENT);

            float acc = 0.f;
            #pragma unroll 16
            for (int j = 0; j < 256; j += 4) {
                float4 wv = *reinterpret_cast<const float4*>(wrow + j);
                float4 sv = *reinterpret_cast<const float4*>(&s_lds[0][c * 256 + j]);
                acc = fmaf(wv.x, sv.x, acc);
                acc = fmaf(wv.y, sv.y, acc);
                acc = fmaf(wv.z, sv.z, acc);
                acc = fmaf(wv.w, sv.w, acc);
            }
            acc += __shfl_xor(acc, 1, 64);
            acc += __shfl_xor(acc, 2, 64);
            acc += __shfl_xor(acc, 4, 64);
            if (c == 0) out[t * O_ + o] += acc;   // exclusive writer
            __syncthreads();                      // protect s_lds before restage
        }
    }
}

extern "C" void kernel_launch(void* const* d_in, const int* in_sizes, int n_in,
                              void* d_out, int out_size, void* d_ws, size_t ws_size,
                              hipStream_t stream)
{
    (void)in_sizes; (void)n_in; (void)out_size;
    const float* X      = (const float*)d_in[0];
    const float* W_in   = (const float*)d_in[1];
    const float* W_res  = (const float*)d_in[2];
    const float* W_out  = (const float*)d_in[3];
    const float* state0 = (const float*)d_in[4];
    float* out = (float*)d_out;

    char* ws    = (char*)d_ws;
    int*  rprog = (int*)ws;
    u32*  ring  = (u32*)(ws + 4096);

    int dmask = (ws_size >= 4096 + (size_t)256 * R_ * 4) ? 255 : 127;

    hipLaunchKernelGGL(esn_init, dim3(1024), dim3(256), 0, stream,
                       X, W_out, out, rprog);
    hipLaunchKernelGGL(esn_main, dim3(G_ + GR_), dim3(BLK), 0, stream,
                       X, W_in, W_res, W_out, state0, out, ring, rprog, dmask);
}

// Round 9
// 13805.766 us; speedup vs baseline: 2.0081x; 1.9243x over previous
//
#include <hip/hip_runtime.h>
#include <hip/hip_fp16.h>
#include <math.h>

// ESN recurrence, round 9: shrink the sync domain.
// Evidence: R5-R8 all = 3.26us/step despite different weight residency
// (VGPR 76..132) -> fabric-bound, not compute/residency-bound. R3 = 2.56us
// with (a) 4-lane u32 publish (ONE 16B transaction; R4+ used lane0 x 2 u64
// stores that land at different times, splitting pollers' detect across
// rounds) and (b) conditional polls (less traffic). R9 restores both, and
// removes sync participants entirely via HISTORY mode: full tagged state
// history in ws (8192 x 2048 u32, no wrap) -> no back-pressure, no rprog,
// NO reader WGs (grid = 128 producers only); readout is a post-kernel
// (kernel-boundary visibility, plain loads). Ring+readers kept as fallback
// if ws < 68MB. Tag protocol unchanged: u32 = (tag=t+1)<<16 | f16(state);
// replay-stale entries are bit-identical (deterministic) -> benign; 0xAA
// poison tag (0xAAAA=43690 > 8191) never matches.

#define R_    2048
#define I_    32
#define O_    32
#define NSTEP 8191
#define G_    128
#define GR_   32
#define BLK   256
#define CAPP  (1u << 24)   // data-poll cap: fail loud, never hang
#define CAPB  (1u << 22)   // back-pressure cap (ring mode only)

typedef unsigned int u32;
typedef unsigned long long u64;

__device__ __forceinline__ float tanh_fast(float u) {
    float e = __expf(2.f * u);            // inf-safe: overflow -> +/-1 exactly
    return 1.f - __fdividef(2.f, e + 1.f);
}
__device__ __forceinline__ u32 pkh(float v, u32 tag) {
    return (tag << 16) | (u32)__half_as_ushort(__float2half(v));
}
__device__ __forceinline__ u64 ald(const u64* p) {
    return __hip_atomic_load(p, __ATOMIC_RELAXED, __HIP_MEMORY_SCOPE_AGENT);
}
__device__ __forceinline__ float h2f(u32 b) {
    return __half2float(__ushort_as_half((unsigned short)(b & 0xFFFFu)));
}

// ws layout: [0,128) rprog[32] (ring mode only)
//   HIST:  [4096, 4096 + 8192*R_*4)   states u32[8192][R_]  (67.1 MB)
//   ring:  [4096, 4096 + (dmask+1)*R_*4) ring u32[][R_]

__global__ __launch_bounds__(256) void esn_init(const float* __restrict__ X,
                                                const float* __restrict__ W_out,
                                                float* __restrict__ out,
                                                int* __restrict__ rprog)
{
    int idx = blockIdx.x * blockDim.x + threadIdx.x;
    if (idx < GR_)
        __hip_atomic_store(&rprog[idx], 0, __ATOMIC_RELAXED,
                           __HIP_MEMORY_SCOPE_AGENT);
    if (idx < NSTEP * O_) {
        int q = idx >> 5;
        int o = idx & 31;
        const float* wrow = W_out + o * (R_ + I_) + R_;
        const float* xrow = X + q * I_;
        float acc = 0.f;
        #pragma unroll
        for (int j = 0; j < I_; ++j) acc = fmaf(wrow[j], xrow[j], acc);
        out[idx] = acc;   // x-part; state part added by readout/reader
    }
}

// post-pass readout (HIST mode): out[t] += W_out[:, :R] @ s_{t+1}
__global__ __launch_bounds__(256) void esn_readout(const u32* __restrict__ states,
                                                   const float* __restrict__ W_out,
                                                   float* __restrict__ out)
{
    __shared__ float s_arr[R_];
    const int t   = blockIdx.x;        // 0..NSTEP-1
    const int tid = threadIdx.x;
    const u64* p64 = (const u64*)(states + (size_t)(t + 1) * R_);
    #pragma unroll
    for (int q = 0; q < 4; ++q) {
        u64 a = *(const u64*)(&p64[q * 256 + tid]);   // plain load: post-kernel
        float2 f; f.x = h2f((u32)a); f.y = h2f((u32)(a >> 32));
        *reinterpret_cast<float2*>(&s_arr[q * 512 + 2 * tid]) = f;
    }
    __syncthreads();
    const int o = tid >> 3, c = tid & 7;
    const float* wrow = W_out + (size_t)o * (R_ + I_) + c * 256;
    float acc = 0.f;
    #pragma unroll 16
    for (int j = 0; j < 256; j += 4) {
        float4 wv = *reinterpret_cast<const float4*>(wrow + j);
        float4 sv = *reinterpret_cast<const float4*>(&s_arr[c * 256 + j]);
        acc = fmaf(wv.x, sv.x, acc); acc = fmaf(wv.y, sv.y, acc);
        acc = fmaf(wv.z, sv.z, acc); acc = fmaf(wv.w, sv.w, acc);
    }
    acc += __shfl_xor(acc, 1, 64);
    acc += __shfl_xor(acc, 2, 64);
    acc += __shfl_xor(acc, 4, 64);
    if (c == 0) out[t * O_ + o] += acc;
}

template <bool HIST>
__global__ __launch_bounds__(BLK)
__attribute__((amdgpu_waves_per_eu(1, 1)))
void esn_main(
    const float* __restrict__ X, const float* __restrict__ W_in,
    const float* __restrict__ W_res, const float* __restrict__ W_out,
    const float* __restrict__ state0, float* __restrict__ out,
    u32* __restrict__ ring, int* __restrict__ rprog, int dmask)
{
    const int tid = threadIdx.x;
    const int g   = blockIdx.x;
    __shared__ float s_lds[2][R_];

    if (g < G_) {
        // ---------------- producer: rows [g*16, g*16+16) ----------------
        const int lane  = tid & 63;
        const int wave  = tid >> 6;
        const int myrow = g * 16 + wave * 4;

        float w[4][32];   // scalar-decomposed: w[i][4k+j] = row myrow+i, col k*256+4*lane+j
        #pragma unroll
        for (int i = 0; i < 4; ++i) {
            const float* wr = W_res + (size_t)(myrow + i) * R_;
            #pragma unroll
            for (int k = 0; k < 8; ++k) {
                float4 v = *reinterpret_cast<const float4*>(wr + k * 256 + 4 * lane);
                w[i][4*k+0] = v.x; w[i][4*k+1] = v.y;
                w[i][4*k+2] = v.z; w[i][4*k+3] = v.w;
            }
        }
        float wi[4];
        #pragma unroll
        for (int i = 0; i < 4; ++i)
            wi[i] = (lane < 32) ? W_in[(size_t)(myrow + i) * I_ + lane] : 0.f;

        #pragma unroll
        for (int q = 0; q < 8; ++q)
            s_lds[0][q * 256 + tid] = state0[q * 256 + tid];
        __syncthreads();

        float xl = (lane < 32) ? X[lane] : 0.f;

        for (int t = 0; t < NSTEP; ++t) {
            if (!HIST) {   // ring mode only: sampled back-pressure
                if ((t & 15) == 0 && t > dmask) {
                    unsigned tries = 0;
                    while (__hip_atomic_load(&rprog[g & (GR_ - 1)], __ATOMIC_RELAXED,
                                             __HIP_MEMORY_SCOPE_AGENT) < t - 64) {
                        if (++tries > CAPB) break;
                        __builtin_amdgcn_s_sleep(16);
                    }
                }
            }

            const float* sbuf = s_lds[t & 1];
            float p0 = wi[0] * xl, p1 = wi[1] * xl, p2 = wi[2] * xl, p3 = wi[3] * xl;
            #pragma unroll
            for (int k = 0; k < 8; ++k) {
                const float4 sv = *reinterpret_cast<const float4*>(
                    &sbuf[k * 256 + 4 * lane]);
                p0 = fmaf(w[0][4*k+0], sv.x, p0); p0 = fmaf(w[0][4*k+1], sv.y, p0);
                p0 = fmaf(w[0][4*k+2], sv.z, p0); p0 = fmaf(w[0][4*k+3], sv.w, p0);
                p1 = fmaf(w[1][4*k+0], sv.x, p1); p1 = fmaf(w[1][4*k+1], sv.y, p1);
                p1 = fmaf(w[1][4*k+2], sv.z, p1); p1 = fmaf(w[1][4*k+3], sv.w, p1);
                p2 = fmaf(w[2][4*k+0], sv.x, p2); p2 = fmaf(w[2][4*k+1], sv.y, p2);
                p2 = fmaf(w[2][4*k+2], sv.z, p2); p2 = fmaf(w[2][4*k+3], sv.w, p2);
                p3 = fmaf(w[3][4*k+0], sv.x, p3); p3 = fmaf(w[3][4*k+1], sv.y, p3);
                p3 = fmaf(w[3][4*k+2], sv.z, p3); p3 = fmaf(w[3][4*k+3], sv.w, p3);
            }
            #pragma unroll
            for (int off = 1; off < 64; off <<= 1) {
                p0 += __shfl_xor(p0, off, 64);
                p1 += __shfl_xor(p1, off, 64);
                p2 += __shfl_xor(p2, off, 64);
                p3 += __shfl_xor(p3, off, 64);
            }
            // publish: 4 lanes x u32 = ONE wave-store = one 16B transaction,
            // so pollers see all 4 rows arrive atomically-together (R3 form).
            {
                const u32 tg = (u32)(t + 1);
                const size_t sb = HIST ? (size_t)(t + 1) * R_
                                       : (size_t)((t + 1) & dmask) * R_;
                if (lane < 4) {
                    float pm = (lane == 0) ? p0 : (lane == 1) ? p1
                             : (lane == 2) ? p2 : p3;
                    __hip_atomic_store(&ring[sb + myrow + lane],
                                       pkh(tanh_fast(pm), tg),
                                       __ATOMIC_RELAXED, __HIP_MEMORY_SCOPE_AGENT);
                }
            }
            if (t == NSTEP - 1) break;

            float xn = (lane < 32) ? X[(size_t)(t + 1) * I_ + lane] : 0.f;

            // poll: conditional (only pending quarters -> minimal fabric
            // traffic), loads grouped before checks (one RTT per round)
            u64 a0 = 0, a1 = 0, a2 = 0, a3 = 0;
            {
                const u32 tg  = (u32)(t + 1);
                const u64 pat = ((u64)tg << 48) | ((u64)tg << 16);
                const u64 msk = 0xFFFF0000FFFF0000ull;
                const size_t sb = HIST ? (size_t)(t + 1) * R_
                                       : (size_t)((t + 1) & dmask) * R_;
                const u64* p64 = (const u64*)(ring + sb);
                unsigned pend = 0xFu, tries = 0;
                while (pend) {
                    u64 b0 = 0, b1 = 0, b2 = 0, b3 = 0;
                    if (pend & 1u) b0 = ald(&p64[0 * 256 + tid]);
                    if (pend & 2u) b1 = ald(&p64[1 * 256 + tid]);
                    if (pend & 4u) b2 = ald(&p64[2 * 256 + tid]);
                    if (pend & 8u) b3 = ald(&p64[3 * 256 + tid]);
                    if ((pend & 1u) && !((b0 ^ pat) & msk)) { a0 = b0; pend &= ~1u; }
                    if ((pend & 2u) && !((b1 ^ pat) & msk)) { a1 = b1; pend &= ~2u; }
                    if ((pend & 4u) && !((b2 ^ pat) & msk)) { a2 = b2; pend &= ~4u; }
                    if ((pend & 8u) && !((b3 ^ pat) & msk)) { a3 = b3; pend &= ~8u; }
                    if (!pend) break;
                    if (++tries > CAPP) break;   // fail loud, never hang
                    __builtin_amdgcn_s_sleep(1);
                }
            }
            // stage into the other buffer (dbuf + one barrier proven safe)
            {
                float* dbuf = s_lds[(t + 1) & 1];
                float2 f;
                f.x = h2f((u32)a0); f.y = h2f((u32)(a0 >> 32));
                *reinterpret_cast<float2*>(&dbuf[0 * 512 + 2 * tid]) = f;
                f.x = h2f((u32)a1); f.y = h2f((u32)(a1 >> 32));
                *reinterpret_cast<float2*>(&dbuf[1 * 512 + 2 * tid]) = f;
                f.x = h2f((u32)a2); f.y = h2f((u32)(a2 >> 32));
                *reinterpret_cast<float2*>(&dbuf[2 * 512 + 2 * tid]) = f;
                f.x = h2f((u32)a3); f.y = h2f((u32)(a3 >> 32));
                *reinterpret_cast<float2*>(&dbuf[3 * 512 + 2 * tid]) = f;
            }
            xl = xn;
            __syncthreads();
        }
    } else if (!HIST) {
        // ---------------- reader (ring mode only) ----------------
        const int r = g - G_;
        const int o = tid >> 3;
        const int c = tid & 7;
        const float* wrow = W_out + (size_t)o * (R_ + I_) + c * 256;

        for (int t = r; t < NSTEP; t += GR_) {
            const u32 tg  = (u32)(t + 1);
            const u64 pat = ((u64)tg << 48) | ((u64)tg << 16);
            const u64 msk = 0xFFFF0000FFFF0000ull;
            const u64* p64 = (const u64*)(ring + (size_t)((t + 1) & dmask) * R_);
            u64 a0 = 0, a1 = 0, a2 = 0, a3 = 0;
            unsigned pend = 0xFu, tries = 0;
            while (pend) {
                u64 b0 = 0, b1 = 0, b2 = 0, b3 = 0;
                if (pend & 1u) b0 = ald(&p64[0 * 256 + tid]);
                if (pend & 2u) b1 = ald(&p64[1 * 256 + tid]);
                if (pend & 4u) b2 = ald(&p64[2 * 256 + tid]);
                if (pend & 8u) b3 = ald(&p64[3 * 256 + tid]);
                if ((pend & 1u) && !((b0 ^ pat) & msk)) { a0 = b0; pend &= ~1u; }
                if ((pend & 2u) && !((b1 ^ pat) & msk)) { a1 = b1; pend &= ~2u; }
                if ((pend & 4u) && !((b2 ^ pat) & msk)) { a2 = b2; pend &= ~4u; }
                if ((pend & 8u) && !((b3 ^ pat) & msk)) { a3 = b3; pend &= ~8u; }
                if (!pend) break;
                if (++tries > CAPP) break;
                __builtin_amdgcn_s_sleep(2);
            }
            float2 f;
            f.x = h2f((u32)a0); f.y = h2f((u32)(a0 >> 32));
            *reinterpret_cast<float2*>(&s_lds[0][0 * 512 + 2 * tid]) = f;
            f.x = h2f((u32)a1); f.y = h2f((u32)(a1 >> 32));
            *reinterpret_cast<float2*>(&s_lds[0][1 * 512 + 2 * tid]) = f;
            f.x = h2f((u32)a2); f.y = h2f((u32)(a2 >> 32));
            *reinterpret_cast<float2*>(&s_lds[0][2 * 512 + 2 * tid]) = f;
            f.x = h2f((u32)a3); f.y = h2f((u32)(a3 >> 32));
            *reinterpret_cast<float2*>(&s_lds[0][3 * 512 + 2 * tid]) = f;
            __syncthreads();
            if (tid == 0)
                __hip_atomic_store(&rprog[r], t, __ATOMIC_RELAXED,
                                   __HIP_MEMORY_SCOPE_AGENT);

            float acc = 0.f;
            #pragma unroll 16
            for (int j = 0; j < 256; j += 4) {
                float4 wv = *reinterpret_cast<const float4*>(wrow + j);
                float4 sv = *reinterpret_cast<const float4*>(&s_lds[0][c * 256 + j]);
                acc = fmaf(wv.x, sv.x, acc); acc = fmaf(wv.y, sv.y, acc);
                acc = fmaf(wv.z, sv.z, acc); acc = fmaf(wv.w, sv.w, acc);
            }
            acc += __shfl_xor(acc, 1, 64);
            acc += __shfl_xor(acc, 2, 64);
            acc += __shfl_xor(acc, 4, 64);
            if (c == 0) out[t * O_ + o] += acc;
            __syncthreads();
        }
    }
}

extern "C" void kernel_launch(void* const* d_in, const int* in_sizes, int n_in,
                              void* d_out, int out_size, void* d_ws, size_t ws_size,
                              hipStream_t stream)
{
    (void)in_sizes; (void)n_in; (void)out_size;
    const float* X      = (const float*)d_in[0];
    const float* W_in   = (const float*)d_in[1];
    const float* W_res  = (const float*)d_in[2];
    const float* W_out  = (const float*)d_in[3];
    const float* state0 = (const float*)d_in[4];
    float* out = (float*)d_out;

    char* ws    = (char*)d_ws;
    int*  rprog = (int*)ws;
    u32*  ring  = (u32*)(ws + 4096);

    const bool hist = ws_size >= 4096 + (size_t)8192 * R_ * 4;   // 67.1 MB

    hipLaunchKernelGGL(esn_init, dim3(1024), dim3(256), 0, stream,
                       X, W_out, out, rprog);
    if (hist) {
        esn_main<true><<<dim3(G_), dim3(BLK), 0, stream>>>(
            X, W_in, W_res, W_out, state0, out, ring, rprog, 0);
        hipLaunchKernelGGL(esn_readout, dim3(NSTEP), dim3(256), 0, stream,
                           ring, W_out, out);
    } else {
        int dmask = (ws_size >= 4096 + (size_t)256 * R_ * 4) ? 255 : 127;
        esn_main<false><<<dim3(G_ + GR_), dim3(BLK), 0, stream>>>(
            X, W_in, W_res, W_out, state0, out, ring, rprog, dmask);
    }
}